// Round 13
// baseline (209.639 us; speedup 1.0000x reference)
//
#include <hip/hip_runtime.h>
#include <math.h>

#define N_NODES 30000
#define N_EDGESN 480000
#define NFEAT 256
#define HEADS 4
#define C0V 64
#define C1V 40
#define HC0 (HEADS*C0V)   // 256
#define HC1 (HEADS*C1V)   // 160
#define NEG_SLOPE 0.2f
#define EPSV 1e-16f
#define KDIM 256
#define KPAD 264

typedef unsigned short ushort_t;
typedef __attribute__((ext_vector_type(8))) short short8v;
typedef __attribute__((ext_vector_type(4))) float f32x4;

__device__ __forceinline__ float lrelu(float x) { return x >= 0.f ? x : x * NEG_SLOPE; }

__device__ __forceinline__ float b2f_lo(unsigned int u) {
  union { unsigned int u; float f; } v; v.u = u << 16; return v.f;
}
__device__ __forceinline__ float b2f_hi(unsigned int u) {
  union { unsigned int u; float f; } v; v.u = u & 0xffff0000u; return v.f;
}
__device__ __forceinline__ unsigned short f2b(float f) {
  union { float f; unsigned int u; } v; v.f = f;
  unsigned int u = v.u + 0x7FFFu + ((v.u >> 16) & 1u);   // round-nearest-even
  return (unsigned short)(u >> 16);
}

// ---- prep: weight transposes + zero deg/fill, one dispatch --------------------
__global__ __launch_bounds__(256) void prep_kernel(const float* __restrict__ W0,
    const float* __restrict__ W1, ushort_t* __restrict__ W0t,
    ushort_t* __restrict__ W1t, int* __restrict__ zp, int zn) {
  const int idx = blockIdx.x * 256 + threadIdx.x;
  constexpr int T0 = NFEAT * HC0;   // 65536
  constexpr int T1 = HC0 * HC1;     // 40960
  if (idx < T0) {
    const int k = idx / HC0, nf = idx - k * HC0;
    W0t[(size_t)nf * NFEAT + k] = f2b(W0[idx]);
  } else if (idx < T0 + T1) {
    const int i2 = idx - T0;
    const int k = i2 / HC1, nf = i2 - k * HC1;
    W1t[(size_t)nf * HC0 + k] = f2b(W1[i2]);
  }
  if (idx < zn) zp[idx] = 0;
}

// ---- MFMA GEMM v3: B in registers, multi-strip blocks, double-buffered A ------
template <int NFW, int CG, bool A_F32, int FUSE, int NT>
__global__ __launch_bounds__(NT) void gemm_mfma3(const void* __restrict__ Ap,
    const ushort_t* __restrict__ Wt, ushort_t* __restrict__ C, int nblk,
    const float* __restrict__ att, float* __restrict__ al, float* __restrict__ ar) {
  constexpr int S = N_NODES / 16;           // 1875 strips (M % 16 == 0)
  constexpr int N = CG * NFW * 16;
  constexpr int NCH = 16 * (KDIM / 8) / NT; // staging chunks per thread
  __shared__ ushort_t As[2][16][KPAD];
  const int tid = threadIdx.x;
  const int lane = tid & 63, cg = tid >> 6;
  const int r_a = lane & 15, kg = lane >> 4;

  short8v B[8][NFW];
#pragma unroll
  for (int ks = 0; ks < 8; ++ks)
#pragma unroll
    for (int f = 0; f < NFW; ++f)
      B[ks][f] = *reinterpret_cast<const short8v*>(
          Wt + (size_t)((cg * NFW + f) * 16 + r_a) * KDIM + ks * 32 + kg * 8);

#define STAGE_LOAD(STRIP, STG)                                                   \
  _Pragma("unroll")                                                              \
  for (int q = 0; q < NCH; ++q) {                                                \
    const int c = tid + q * NT;                                                  \
    const int r = c >> 5, ko = (c & 31) * 8;                                     \
    if (A_F32) {                                                                 \
      const float* A = (const float*)Ap + (size_t)((STRIP) * 16 + r) * KDIM + ko;\
      const float4 lo = *reinterpret_cast<const float4*>(A);                     \
      const float4 hi = *reinterpret_cast<const float4*>(A + 4);                 \
      STG[q].x = (unsigned)f2b(lo.x) | ((unsigned)f2b(lo.y) << 16);              \
      STG[q].y = (unsigned)f2b(lo.z) | ((unsigned)f2b(lo.w) << 16);              \
      STG[q].z = (unsigned)f2b(hi.x) | ((unsigned)f2b(hi.y) << 16);              \
      STG[q].w = (unsigned)f2b(hi.z) | ((unsigned)f2b(hi.w) << 16);              \
    } else {                                                                     \
      STG[q] = *reinterpret_cast<const uint4*>(                                  \
          (const ushort_t*)Ap + (size_t)((STRIP) * 16 + r) * KDIM + ko);         \
    }                                                                            \
  }
#define STAGE_WRITE(BUF, STG)                                                    \
  _Pragma("unroll")                                                              \
  for (int q = 0; q < NCH; ++q) {                                                \
    const int c = tid + q * NT;                                                  \
    const int r = c >> 5, ko = (c & 31) * 8;                                     \
    *reinterpret_cast<uint4*>(&As[BUF][r][ko]) = STG[q];                         \
  }

  int strip = blockIdx.x;
  {
    uint4 stg[NCH];
    STAGE_LOAD(strip, stg)
    STAGE_WRITE(0, stg)
  }
  __syncthreads();

  int buf = 0;
  while (true) {
    const int next = strip + nblk;
    const bool has_next = next < S;
    uint4 stg[NCH];
    if (has_next) { STAGE_LOAD(next, stg) }   // loads in flight during compute

    f32x4 acc[NFW];
#pragma unroll
    for (int f = 0; f < NFW; ++f) acc[f] = (f32x4){0.f, 0.f, 0.f, 0.f};
#pragma unroll
    for (int ks = 0; ks < 8; ++ks) {
      const short8v a =
          *reinterpret_cast<const short8v*>(&As[buf][r_a][ks * 32 + kg * 8]);
#pragma unroll
      for (int f = 0; f < NFW; ++f)
        acc[f] = __builtin_amdgcn_mfma_f32_16x16x32_bf16(a, B[ks][f], acc[f], 0, 0, 0);
    }
    const int row0 = strip * 16;
#pragma unroll
    for (int f = 0; f < NFW; ++f) {
#pragma unroll
      for (int r = 0; r < 4; ++r) {
        C[(size_t)(row0 + kg * 4 + r) * N + (cg * NFW + f) * 16 + r_a] =
            f2b(acc[f][r]);
      }
    }
    if (FUSE == 1) {
      float hpl[4] = {0.f, 0.f, 0.f, 0.f}, hpr[4] = {0.f, 0.f, 0.f, 0.f};
#pragma unroll
      for (int f = 0; f < NFW; ++f) {
        const int cc = f * 16 + r_a;
        const float wlv = att[cg * 128 + cc];
        const float wrv = att[cg * 128 + 64 + cc];
#pragma unroll
        for (int r = 0; r < 4; ++r) {
          hpl[r] = fmaf(acc[f][r], wlv, hpl[r]);
          hpr[r] = fmaf(acc[f][r], wrv, hpr[r]);
        }
      }
#pragma unroll
      for (int o = 1; o < 16; o <<= 1) {
#pragma unroll
        for (int r = 0; r < 4; ++r) {
          hpl[r] += __shfl_xor(hpl[r], o);
          hpr[r] += __shfl_xor(hpr[r], o);
        }
      }
      if (r_a == 0) {
#pragma unroll
        for (int r = 0; r < 4; ++r) {
          const int row = row0 + kg * 4 + r;
          al[(size_t)row * 4 + cg] = hpl[r];
          ar[(size_t)row * 4 + cg] = hpr[r];
        }
      }
    } else if (FUSE == 2) {
      float hpa[4] = {0,0,0,0}, hpb[4] = {0,0,0,0};
      float hra[4] = {0,0,0,0}, hrb[4] = {0,0,0,0};
#pragma unroll
      for (int f = 0; f < NFW; ++f) {
        const int col = cg * 80 + f * 16 + r_a;
        const int hd = col / 40;
        const int cc = col - hd * 40;
        const float wlv = att[hd * 80 + cc];
        const float wrv = att[hd * 80 + 40 + cc];
        const bool isB = (hd & 1);
#pragma unroll
        for (int r = 0; r < 4; ++r) {
          const float v = acc[f][r];
          if (isB) { hpb[r] = fmaf(v, wlv, hpb[r]); hrb[r] = fmaf(v, wrv, hrb[r]); }
          else     { hpa[r] = fmaf(v, wlv, hpa[r]); hra[r] = fmaf(v, wrv, hra[r]); }
        }
      }
#pragma unroll
      for (int o = 1; o < 16; o <<= 1) {
#pragma unroll
        for (int r = 0; r < 4; ++r) {
          hpa[r] += __shfl_xor(hpa[r], o); hpb[r] += __shfl_xor(hpb[r], o);
          hra[r] += __shfl_xor(hra[r], o); hrb[r] += __shfl_xor(hrb[r], o);
        }
      }
      if (r_a == 0) {
#pragma unroll
        for (int r = 0; r < 4; ++r) {
          const int row = row0 + kg * 4 + r;
          al[(size_t)row * 4 + cg * 2 + 0] = hpa[r];
          al[(size_t)row * 4 + cg * 2 + 1] = hpb[r];
          ar[(size_t)row * 4 + cg * 2 + 0] = hra[r];
          ar[(size_t)row * 4 + cg * 2 + 1] = hrb[r];
        }
      }
    }

    if (!has_next) break;
    STAGE_WRITE(buf ^ 1, stg)
    __syncthreads();
    strip = next; buf ^= 1;
  }
#undef STAGE_LOAD
#undef STAGE_WRITE
}

// ---- CSR build ----------------------------------------------------------------
__global__ void hist_kernel(const int* __restrict__ src, int* __restrict__ deg, int E) {
  const int e = blockIdx.x * blockDim.x + threadIdx.x;
  if (e < E) atomicAdd(&deg[src[e]], 1);
}

__global__ __launch_bounds__(1024) void scan_kernel(const int* __restrict__ deg,
    int* __restrict__ rowstart, int n) {
  __shared__ int carry;
  __shared__ int wsum[16];
  const int tid = threadIdx.x;
  const int lane = tid & 63, w = tid >> 6;
  if (tid == 0) { carry = 0; rowstart[0] = 0; }
  __syncthreads();
  for (int base = 0; base < n; base += 1024) {
    const int idx = base + tid;
    int x = (idx < n) ? deg[idx] : 0;
#pragma unroll
    for (int o = 1; o < 64; o <<= 1) { int y = __shfl_up(x, o); if (lane >= o) x += y; }
    if (lane == 63) wsum[w] = x;
    __syncthreads();
    if (w == 0) {
      int s = (lane < 16) ? wsum[lane] : 0;
#pragma unroll
      for (int o = 1; o < 16; o <<= 1) { int y = __shfl_up(s, o); if (lane >= o) s += y; }
      if (lane < 16) wsum[lane] = s;
    }
    __syncthreads();
    const int add = (w > 0 ? wsum[w - 1] : 0) + carry;
    if (idx < n) rowstart[idx + 1] = x + add;
    __syncthreads();
    if (tid == 0) carry += wsum[15];
    __syncthreads();
  }
}

__global__ void scatter_kernel(const int* __restrict__ src, const int* __restrict__ dst,
    const int* __restrict__ rowstart, int* __restrict__ fill, int* __restrict__ scol,
    int E) {
  const int e = blockIdx.x * blockDim.x + threadIdx.x;
  if (e < E) {
    const int r = src[e];
    const int pos = rowstart[r] + atomicAdd(&fill[r], 1);
    scol[pos] = dst[e];
  }
}

// ---- agg v7 (layer 0): head-sliced, XCD-L2-resident gather --------------------
// One wave = one (node, head). blockIdx%8 ~ XCD; head=(blockIdx&7)&3 -> each XCD
// gathers from ONE head's 3.84MB h-slice (fits 4MB per-XCD L2). 8 lanes/edge
// group -> 8 edges in flight. Normalize-late (single pass).
__global__ __launch_bounds__(256) void gat_agg7(const ushort_t* __restrict__ h,
    const float* __restrict__ al, const float* __restrict__ ar,
    const int* __restrict__ rowstart, const int* __restrict__ scol,
    const float* __restrict__ bias, ushort_t* __restrict__ outp) {
  const int hb = blockIdx.x & 7;
  const int head = hb & 3;
  const int half = hb >> 2;
  const int nodeblk = blockIdx.x >> 3;            // 0..3749
  const int wid = threadIdx.x >> 6, lane = threadIdx.x & 63;
  const int i = (half * 3750 + nodeblk) * 4 + wid;  // covers 0..29999 per head
  const int s0 = rowstart[i], s1 = rowstart[i + 1];

  const float al_h = al[(size_t)i * 4 + head];
  const float es_h = __expf(lrelu(al_h + ar[(size_t)i * 4 + head]));

  const int g  = lane >> 3;        // 8 groups of 8 lanes; all active
  const int cl = lane & 7;         // lane's 8 channels within the head
  const ushort_t* hh = h + head * 64;   // head slice base (row-offset below)

  float t = 0.f;
  float acc[8];
#pragma unroll
  for (int k = 0; k < 8; ++k) acc[k] = 0.f;

  if (g == 0) {   // self-loop (unnormalized)
    const uint4 hv = *reinterpret_cast<const uint4*>(hh + (size_t)i * HC0 + cl * 8);
    acc[0] = es_h * b2f_lo(hv.x); acc[1] = es_h * b2f_hi(hv.x);
    acc[2] = es_h * b2f_lo(hv.y); acc[3] = es_h * b2f_hi(hv.y);
    acc[4] = es_h * b2f_lo(hv.z); acc[5] = es_h * b2f_hi(hv.z);
    acc[6] = es_h * b2f_lo(hv.w); acc[7] = es_h * b2f_hi(hv.w);
  }

#define FMA8(W, HV) \
  acc[0] = fmaf(W, b2f_lo(HV.x), acc[0]); acc[1] = fmaf(W, b2f_hi(HV.x), acc[1]); \
  acc[2] = fmaf(W, b2f_lo(HV.y), acc[2]); acc[3] = fmaf(W, b2f_hi(HV.y), acc[3]); \
  acc[4] = fmaf(W, b2f_lo(HV.z), acc[4]); acc[5] = fmaf(W, b2f_hi(HV.z), acc[5]); \
  acc[6] = fmaf(W, b2f_lo(HV.w), acc[6]); acc[7] = fmaf(W, b2f_hi(HV.w), acc[7])

  {
    int e = s0 + g;
    int ja = scol[e];              // padded scol: safe to LOAD past s1
    int jb = scol[e + 8];
    for (; e + 8 < s1; e += 16) {
      const int jc = scol[e + 16];
      const int jd = scol[e + 24];
      const float ara = ar[(size_t)ja * 4 + head];
      const float arb = ar[(size_t)jb * 4 + head];
      const uint4 ha = *reinterpret_cast<const uint4*>(hh + (size_t)ja * HC0 + cl * 8);
      const uint4 hb = *reinterpret_cast<const uint4*>(hh + (size_t)jb * HC0 + cl * 8);
      const float wa = __expf(lrelu(al_h + ara));
      const float wb = __expf(lrelu(al_h + arb));
      t += wa + wb;
      FMA8(wa, ha); FMA8(wb, hb);
      ja = jc; jb = jd;
    }
    if (e < s1) {
      const float ara = ar[(size_t)ja * 4 + head];
      const uint4 ha = *reinterpret_cast<const uint4*>(hh + (size_t)ja * HC0 + cl * 8);
      const float wa = __expf(lrelu(al_h + ara));
      t += wa;
      FMA8(wa, ha);
    }
  }
#undef FMA8

  // combine the 8 groups (each group's lanes hold identical t)
  t += __shfl_xor(t, 8); t += __shfl_xor(t, 16); t += __shfl_xor(t, 32);
  const float inv = 1.f / (t + es_h + EPSV);
#pragma unroll
  for (int k = 0; k < 8; ++k) {
    acc[k] += __shfl_xor(acc[k], 8);
    acc[k] += __shfl_xor(acc[k], 16);
    acc[k] += __shfl_xor(acc[k], 32);
  }
  if (g == 0) {
    const float4 blo = *reinterpret_cast<const float4*>(bias + head * 64 + cl * 8);
    const float4 bhi = *reinterpret_cast<const float4*>(bias + head * 64 + cl * 8 + 4);
    uint4 st;
    st.x = (unsigned)f2b(fmaxf(acc[0] * inv + blo.x, 0.f)) |
           ((unsigned)f2b(fmaxf(acc[1] * inv + blo.y, 0.f)) << 16);
    st.y = (unsigned)f2b(fmaxf(acc[2] * inv + blo.z, 0.f)) |
           ((unsigned)f2b(fmaxf(acc[3] * inv + blo.w, 0.f)) << 16);
    st.z = (unsigned)f2b(fmaxf(acc[4] * inv + bhi.x, 0.f)) |
           ((unsigned)f2b(fmaxf(acc[5] * inv + bhi.y, 0.f)) << 16);
    st.w = (unsigned)f2b(fmaxf(acc[6] * inv + bhi.z, 0.f)) |
           ((unsigned)f2b(fmaxf(acc[7] * inv + bhi.w, 0.f)) << 16);
    *reinterpret_cast<uint4*>(outp + (size_t)i * HC0 + head * 64 + cl * 8) = st;
  }
}

// ---- agg v6c (layer 1): single pass, normalize after aggregation --------------
template <int C, bool CONCAT_RELU>
__global__ __launch_bounds__(256) void gat_agg6(const ushort_t* __restrict__ h,
    const float* __restrict__ al, const float* __restrict__ ar,
    const int* __restrict__ rowstart, const int* __restrict__ scol,
    const float* __restrict__ bias, void* __restrict__ outv, int n) {
  constexpr int ROW = HEADS * C;     // 160
  constexpr int LPG = ROW / 8;       // 20
  constexpr int NG  = 64 / LPG;      // 3
  __shared__ float smA[CONCAT_RELU ? 1 : 4][CONCAT_RELU ? 1 : NG]
                      [CONCAT_RELU ? 1 : ROW];
  __shared__ float smT[CONCAT_RELU ? 1 : 4][CONCAT_RELU ? 1 : NG * LPG];
  const int wid = threadIdx.x >> 6, lane = threadIdx.x & 63;
  const int i = blockIdx.x * 4 + wid;
  if (i >= n) return;
  const int s0 = rowstart[i], s1 = rowstart[i + 1];

  const float4 al4 = *reinterpret_cast<const float4*>(al + (size_t)i * 4);
  const float4 ari = *reinterpret_cast<const float4*>(ar + (size_t)i * 4);
  const float es0 = __expf(lrelu(al4.x + ari.x));
  const float es1 = __expf(lrelu(al4.y + ari.y));
  const float es2 = __expf(lrelu(al4.z + ari.z));
  const float es3 = __expf(lrelu(al4.w + ari.w));

  const int g  = lane / LPG;
  const int cl = lane - g * LPG;
  const bool act = g < NG;
  const int hd = (cl * 8) / C;
  const float al_h = hd < 2 ? (hd == 0 ? al4.x : al4.y) : (hd == 2 ? al4.z : al4.w);
  const float es_h = hd < 2 ? (hd == 0 ? es0 : es1) : (hd == 2 ? es2 : es3);

  float t = 0.f;
  float acc[8];
#pragma unroll
  for (int k = 0; k < 8; ++k) acc[k] = 0.f;

  if (g == 0) {
    const uint4 hv = *reinterpret_cast<const uint4*>(h + (size_t)i * ROW + cl * 8);
    acc[0] = es_h * b2f_lo(hv.x); acc[1] = es_h * b2f_hi(hv.x);
    acc[2] = es_h * b2f_lo(hv.y); acc[3] = es_h * b2f_hi(hv.y);
    acc[4] = es_h * b2f_lo(hv.z); acc[5] = es_h * b2f_hi(hv.z);
    acc[6] = es_h * b2f_lo(hv.w); acc[7] = es_h * b2f_hi(hv.w);
  }

#define FMA8(W, HV) \
  acc[0] = fmaf(W, b2f_lo(HV.x), acc[0]); acc[1] = fmaf(W, b2f_hi(HV.x), acc[1]); \
  acc[2] = fmaf(W, b2f_lo(HV.y), acc[2]); acc[3] = fmaf(W, b2f_hi(HV.y), acc[3]); \
  acc[4] = fmaf(W, b2f_lo(HV.z), acc[4]); acc[5] = fmaf(W, b2f_hi(HV.z), acc[5]); \
  acc[6] = fmaf(W, b2f_lo(HV.w), acc[6]); acc[7] = fmaf(W, b2f_hi(HV.w), acc[7])

  if (act) {
    int e = s0 + g;
    int ja = scol[e];
    int jb = scol[e + NG];
    for (; e + NG < s1; e += 2 * NG) {
      const int jc = scol[e + 2 * NG];
      const int jd = scol[e + 3 * NG];
      const float ara = ar[(size_t)ja * 4 + hd];
      const float arb = ar[(size_t)jb * 4 + hd];
      const uint4 ha = *reinterpret_cast<const uint4*>(h + (size_t)ja * ROW + cl * 8);
      const uint4 hb = *reinterpret_cast<const uint4*>(h + (size_t)jb * ROW + cl * 8);
      const float wa = __expf(lrelu(al_h + ara));
      const float wb = __expf(lrelu(al_h + arb));
      t += wa + wb;
      FMA8(wa, ha); FMA8(wb, hb);
      ja = jc; jb = jd;
    }
    if (e < s1) {
      const float ara = ar[(size_t)ja * 4 + hd];
      const uint4 ha = *reinterpret_cast<const uint4*>(h + (size_t)ja * ROW + cl * 8);
      const float wa = __expf(lrelu(al_h + ara));
      t += wa;
      FMA8(wa, ha);
    }
  }
#undef FMA8

  {
    if (act) {
#pragma unroll
      for (int k = 0; k < 8; ++k) smA[wid][g][cl * 8 + k] = acc[k];
      smT[wid][g * LPG + cl] = t;
    }
    __syncthreads();
    if (lane < C) {
      const float es[4] = {es0, es1, es2, es3};
      float s = 0.f;
#pragma unroll
      for (int hh = 0; hh < HEADS; ++hh) {
        float den = es[hh];
#pragma unroll
        for (int gg = 0; gg < NG; ++gg)
          den += smT[wid][gg * LPG + hh * 5];   // ONE representative per group
        float chan = 0.f;
#pragma unroll
        for (int gg = 0; gg < NG; ++gg) chan += smA[wid][gg][hh * C + lane];
        s += chan / (den + EPSV);
      }
      ((float*)outv)[(size_t)i * C + lane] = s * 0.25f + bias[lane];
    }
  }
}

// ---- launch -------------------------------------------------------------------
extern "C" void kernel_launch(void* const* d_in, const int* in_sizes, int n_in,
                              void* d_out, int out_size, void* d_ws, size_t ws_size,
                              hipStream_t stream) {
  const float* x    = (const float*)d_in[0];
  const int*   ei   = (const int*)d_in[1];
  const float* w0   = (const float*)d_in[2];
  const float* att0 = (const float*)d_in[3];
  const float* b0   = (const float*)d_in[4];
  const float* w1   = (const float*)d_in[5];
  const float* att1 = (const float*)d_in[6];
  const float* b1   = (const float*)d_in[7];
  float* out = (float*)d_out;

  char* ws = (char*)d_ws;
  size_t off = 0;
  auto alloc = [&](size_t bytes) -> void* {
    void* p = ws + off;
    off += (bytes + 255) & ~(size_t)255;
    return p;
  };
  ushort_t* h0b = (ushort_t*)alloc((size_t)N_NODES * HC0 * 2);  // 15.4 MB
  ushort_t* o0b = (ushort_t*)alloc((size_t)N_NODES * HC0 * 2);  // 15.4 MB
  float* al0 = (float*)alloc((size_t)N_NODES * HEADS * 4);
  float* ar0 = (float*)alloc((size_t)N_NODES * HEADS * 4);
  ushort_t* w0t = (ushort_t*)alloc((size_t)HC0 * NFEAT * 2);    // 128 KB
  ushort_t* w1t = (ushort_t*)alloc((size_t)HC1 * HC0 * 2);      // 80 KB
  int* deg      = (int*)alloc((size_t)N_NODES * 4);
  int* fill     = (int*)alloc((size_t)N_NODES * 4);   // adjacent to deg
  int* rowstart = (int*)alloc((size_t)(N_NODES + 1) * 4);
  int* scol     = (int*)alloc((size_t)(N_EDGESN + 64) * 4);  // +64 pad: no clamps
  ushort_t* h1b = h0b;   // layer-0 h dead after layer-0 agg
  float* al1 = al0;
  float* ar1 = ar0;

  const int* srcp = ei;
  const int* dstp = ei + N_EDGESN;

  const int ztot = (int)(fill - deg) + N_NODES;     // covers deg + fill
  constexpr int PREPN = NFEAT * HC0 + HC0 * HC1;    // 106496 >= ztot
  prep_kernel<<<(PREPN + 255) / 256, 256, 0, stream>>>(w0, w1, w0t, w1t, deg, ztot);
  hist_kernel<<<(N_EDGESN + 255) / 256, 256, 0, stream>>>(srcp, deg, N_EDGESN);
  scan_kernel<<<1, 1024, 0, stream>>>(deg, rowstart, N_NODES);
  scatter_kernel<<<(N_EDGESN + 255) / 256, 256, 0, stream>>>(srcp, dstp, rowstart,
                                                             fill, scol, N_EDGESN);

  // layer 0
  gemm_mfma3<4, 4, true, 1, 256><<<625, 256, 0, stream>>>(
      x, w0t, h0b, 625, att0, al0, ar0);
  gat_agg7<<<30000, 256, 0, stream>>>(h0b, al0, ar0, rowstart, scol, b0, o0b);
  // layer 1
  gemm_mfma3<5, 2, false, 2, 128><<<938, 128, 0, stream>>>(
      o0b, w1t, h1b, 938, att1, al1, ar1);
  gat_agg6<C1V, false><<<(N_NODES + 3) / 4, 256, 0, stream>>>(
      h1b, al1, ar1, rowstart, scol, b1, out, N_NODES);
}

// Round 14
// 195.427 us; speedup vs baseline: 1.0727x; 1.0727x over previous
//
#include <hip/hip_runtime.h>
#include <math.h>

#define N_NODES 30000
#define N_EDGESN 480000
#define NFEAT 256
#define HEADS 4
#define C0V 64
#define C1V 40
#define HC0 (HEADS*C0V)   // 256
#define HC1 (HEADS*C1V)   // 160
#define NEG_SLOPE 0.2f
#define EPSV 1e-16f
#define KDIM 256
#define KPAD 264

typedef unsigned short ushort_t;
typedef __attribute__((ext_vector_type(8))) short short8v;
typedef __attribute__((ext_vector_type(4))) float f32x4;

__device__ __forceinline__ float lrelu(float x) { return x >= 0.f ? x : x * NEG_SLOPE; }

__device__ __forceinline__ float b2f_lo(unsigned int u) {
  union { unsigned int u; float f; } v; v.u = u << 16; return v.f;
}
__device__ __forceinline__ float b2f_hi(unsigned int u) {
  union { unsigned int u; float f; } v; v.u = u & 0xffff0000u; return v.f;
}
__device__ __forceinline__ unsigned short f2b(float f) {
  union { float f; unsigned int u; } v; v.f = f;
  unsigned int u = v.u + 0x7FFFu + ((v.u >> 16) & 1u);   // round-nearest-even
  return (unsigned short)(u >> 16);
}

// ---- prep: weight transposes + zero deg/fill, one dispatch --------------------
__global__ __launch_bounds__(256) void prep_kernel(const float* __restrict__ W0,
    const float* __restrict__ W1, ushort_t* __restrict__ W0t,
    ushort_t* __restrict__ W1t, int* __restrict__ zp, int zn) {
  const int idx = blockIdx.x * 256 + threadIdx.x;
  constexpr int T0 = NFEAT * HC0;   // 65536
  constexpr int T1 = HC0 * HC1;     // 40960
  if (idx < T0) {
    const int k = idx / HC0, nf = idx - k * HC0;
    W0t[(size_t)nf * NFEAT + k] = f2b(W0[idx]);
  } else if (idx < T0 + T1) {
    const int i2 = idx - T0;
    const int k = i2 / HC1, nf = i2 - k * HC1;
    W1t[(size_t)nf * HC0 + k] = f2b(W1[i2]);
  }
  if (idx < zn) zp[idx] = 0;
}

// ---- MFMA GEMM v3: B in registers, multi-strip blocks, double-buffered A ------
template <int NFW, int CG, bool A_F32, int FUSE, int NT>
__global__ __launch_bounds__(NT) void gemm_mfma3(const void* __restrict__ Ap,
    const ushort_t* __restrict__ Wt, ushort_t* __restrict__ C, int nblk,
    const float* __restrict__ att, float* __restrict__ al, float* __restrict__ ar) {
  constexpr int S = N_NODES / 16;           // 1875 strips (M % 16 == 0)
  constexpr int N = CG * NFW * 16;
  constexpr int NCH = 16 * (KDIM / 8) / NT; // staging chunks per thread
  __shared__ ushort_t As[2][16][KPAD];
  const int tid = threadIdx.x;
  const int lane = tid & 63, cg = tid >> 6;
  const int r_a = lane & 15, kg = lane >> 4;

  short8v B[8][NFW];
#pragma unroll
  for (int ks = 0; ks < 8; ++ks)
#pragma unroll
    for (int f = 0; f < NFW; ++f)
      B[ks][f] = *reinterpret_cast<const short8v*>(
          Wt + (size_t)((cg * NFW + f) * 16 + r_a) * KDIM + ks * 32 + kg * 8);

#define STAGE_LOAD(STRIP, STG)                                                   \
  _Pragma("unroll")                                                              \
  for (int q = 0; q < NCH; ++q) {                                                \
    const int c = tid + q * NT;                                                  \
    const int r = c >> 5, ko = (c & 31) * 8;                                     \
    if (A_F32) {                                                                 \
      const float* A = (const float*)Ap + (size_t)((STRIP) * 16 + r) * KDIM + ko;\
      const float4 lo = *reinterpret_cast<const float4*>(A);                     \
      const float4 hi = *reinterpret_cast<const float4*>(A + 4);                 \
      STG[q].x = (unsigned)f2b(lo.x) | ((unsigned)f2b(lo.y) << 16);              \
      STG[q].y = (unsigned)f2b(lo.z) | ((unsigned)f2b(lo.w) << 16);              \
      STG[q].z = (unsigned)f2b(hi.x) | ((unsigned)f2b(hi.y) << 16);              \
      STG[q].w = (unsigned)f2b(hi.z) | ((unsigned)f2b(hi.w) << 16);              \
    } else {                                                                     \
      STG[q] = *reinterpret_cast<const uint4*>(                                  \
          (const ushort_t*)Ap + (size_t)((STRIP) * 16 + r) * KDIM + ko);         \
    }                                                                            \
  }
#define STAGE_WRITE(BUF, STG)                                                    \
  _Pragma("unroll")                                                              \
  for (int q = 0; q < NCH; ++q) {                                                \
    const int c = tid + q * NT;                                                  \
    const int r = c >> 5, ko = (c & 31) * 8;                                     \
    *reinterpret_cast<uint4*>(&As[BUF][r][ko]) = STG[q];                         \
  }

  int strip = blockIdx.x;
  {
    uint4 stg[NCH];
    STAGE_LOAD(strip, stg)
    STAGE_WRITE(0, stg)
  }
  __syncthreads();

  int buf = 0;
  while (true) {
    const int next = strip + nblk;
    const bool has_next = next < S;
    uint4 stg[NCH];
    if (has_next) { STAGE_LOAD(next, stg) }   // loads in flight during compute

    f32x4 acc[NFW];
#pragma unroll
    for (int f = 0; f < NFW; ++f) acc[f] = (f32x4){0.f, 0.f, 0.f, 0.f};
#pragma unroll
    for (int ks = 0; ks < 8; ++ks) {
      const short8v a =
          *reinterpret_cast<const short8v*>(&As[buf][r_a][ks * 32 + kg * 8]);
#pragma unroll
      for (int f = 0; f < NFW; ++f)
        acc[f] = __builtin_amdgcn_mfma_f32_16x16x32_bf16(a, B[ks][f], acc[f], 0, 0, 0);
    }
    const int row0 = strip * 16;
#pragma unroll
    for (int f = 0; f < NFW; ++f) {
#pragma unroll
      for (int r = 0; r < 4; ++r) {
        C[(size_t)(row0 + kg * 4 + r) * N + (cg * NFW + f) * 16 + r_a] =
            f2b(acc[f][r]);
      }
    }
    if (FUSE == 1) {
      float hpl[4] = {0.f, 0.f, 0.f, 0.f}, hpr[4] = {0.f, 0.f, 0.f, 0.f};
#pragma unroll
      for (int f = 0; f < NFW; ++f) {
        const int cc = f * 16 + r_a;
        const float wlv = att[cg * 128 + cc];
        const float wrv = att[cg * 128 + 64 + cc];
#pragma unroll
        for (int r = 0; r < 4; ++r) {
          hpl[r] = fmaf(acc[f][r], wlv, hpl[r]);
          hpr[r] = fmaf(acc[f][r], wrv, hpr[r]);
        }
      }
#pragma unroll
      for (int o = 1; o < 16; o <<= 1) {
#pragma unroll
        for (int r = 0; r < 4; ++r) {
          hpl[r] += __shfl_xor(hpl[r], o);
          hpr[r] += __shfl_xor(hpr[r], o);
        }
      }
      if (r_a == 0) {
#pragma unroll
        for (int r = 0; r < 4; ++r) {
          const int row = row0 + kg * 4 + r;
          al[(size_t)row * 4 + cg] = hpl[r];
          ar[(size_t)row * 4 + cg] = hpr[r];
        }
      }
    } else if (FUSE == 2) {
      float hpa[4] = {0,0,0,0}, hpb[4] = {0,0,0,0};
      float hra[4] = {0,0,0,0}, hrb[4] = {0,0,0,0};
#pragma unroll
      for (int f = 0; f < NFW; ++f) {
        const int col = cg * 80 + f * 16 + r_a;
        const int hd = col / 40;
        const int cc = col - hd * 40;
        const float wlv = att[hd * 80 + cc];
        const float wrv = att[hd * 80 + 40 + cc];
        const bool isB = (hd & 1);
#pragma unroll
        for (int r = 0; r < 4; ++r) {
          const float v = acc[f][r];
          if (isB) { hpb[r] = fmaf(v, wlv, hpb[r]); hrb[r] = fmaf(v, wrv, hrb[r]); }
          else     { hpa[r] = fmaf(v, wlv, hpa[r]); hra[r] = fmaf(v, wrv, hra[r]); }
        }
      }
#pragma unroll
      for (int o = 1; o < 16; o <<= 1) {
#pragma unroll
        for (int r = 0; r < 4; ++r) {
          hpa[r] += __shfl_xor(hpa[r], o); hpb[r] += __shfl_xor(hpb[r], o);
          hra[r] += __shfl_xor(hra[r], o); hrb[r] += __shfl_xor(hrb[r], o);
        }
      }
      if (r_a == 0) {
#pragma unroll
        for (int r = 0; r < 4; ++r) {
          const int row = row0 + kg * 4 + r;
          al[(size_t)row * 4 + cg * 2 + 0] = hpa[r];
          al[(size_t)row * 4 + cg * 2 + 1] = hpb[r];
          ar[(size_t)row * 4 + cg * 2 + 0] = hra[r];
          ar[(size_t)row * 4 + cg * 2 + 1] = hrb[r];
        }
      }
    }

    if (!has_next) break;
    STAGE_WRITE(buf ^ 1, stg)
    __syncthreads();
    strip = next; buf ^= 1;
  }
#undef STAGE_LOAD
#undef STAGE_WRITE
}

// ---- CSR build ----------------------------------------------------------------
__global__ void hist_kernel(const int* __restrict__ src, int* __restrict__ deg, int E) {
  const int e = blockIdx.x * blockDim.x + threadIdx.x;
  if (e < E) atomicAdd(&deg[src[e]], 1);
}

__global__ __launch_bounds__(1024) void scan_kernel(const int* __restrict__ deg,
    int* __restrict__ rowstart, int n) {
  __shared__ int carry;
  __shared__ int wsum[16];
  const int tid = threadIdx.x;
  const int lane = tid & 63, w = tid >> 6;
  if (tid == 0) { carry = 0; rowstart[0] = 0; }
  __syncthreads();
  for (int base = 0; base < n; base += 1024) {
    const int idx = base + tid;
    int x = (idx < n) ? deg[idx] : 0;
#pragma unroll
    for (int o = 1; o < 64; o <<= 1) { int y = __shfl_up(x, o); if (lane >= o) x += y; }
    if (lane == 63) wsum[w] = x;
    __syncthreads();
    if (w == 0) {
      int s = (lane < 16) ? wsum[lane] : 0;
#pragma unroll
      for (int o = 1; o < 16; o <<= 1) { int y = __shfl_up(s, o); if (lane >= o) s += y; }
      if (lane < 16) wsum[lane] = s;
    }
    __syncthreads();
    const int add = (w > 0 ? wsum[w - 1] : 0) + carry;
    if (idx < n) rowstart[idx + 1] = x + add;
    __syncthreads();
    if (tid == 0) carry += wsum[15];
    __syncthreads();
  }
}

__global__ void scatter_kernel(const int* __restrict__ src, const int* __restrict__ dst,
    const int* __restrict__ rowstart, int* __restrict__ fill, int* __restrict__ scol,
    int E) {
  const int e = blockIdx.x * blockDim.x + threadIdx.x;
  if (e < E) {
    const int r = src[e];
    const int pos = rowstart[r] + atomicAdd(&fill[r], 1);
    scol[pos] = dst[e];
  }
}

// ---- agg v6d: single pass, normalize late, UNROLL-4 gather (padded scol) ------
// 4 prefetched indices -> 4 h-row + 4 ar + 4 scol loads in flight per wave.
// No ew buffer, no index clamps (scol padded by 64 entries).
template <int C, bool CONCAT_RELU>
__global__ __launch_bounds__(256) void gat_agg6(const ushort_t* __restrict__ h,
    const float* __restrict__ al, const float* __restrict__ ar,
    const int* __restrict__ rowstart, const int* __restrict__ scol,
    const float* __restrict__ bias, void* __restrict__ outv, int n) {
  constexpr int ROW = HEADS * C;     // 256 / 160
  constexpr int LPG = ROW / 8;       // lanes per group: 32 / 20
  constexpr int NG  = 64 / LPG;      // groups: 2 / 3
  __shared__ float smA[CONCAT_RELU ? 1 : 4][CONCAT_RELU ? 1 : NG]
                      [CONCAT_RELU ? 1 : ROW];
  __shared__ float smT[CONCAT_RELU ? 1 : 4][CONCAT_RELU ? 1 : NG * LPG];
  const int wid = threadIdx.x >> 6, lane = threadIdx.x & 63;
  const int i = blockIdx.x * 4 + wid;
  if (i >= n) return;                // never taken (30000 % 4 == 0)
  const int s0 = rowstart[i], s1 = rowstart[i + 1];

  const float4 al4 = *reinterpret_cast<const float4*>(al + (size_t)i * 4);
  const float4 ari = *reinterpret_cast<const float4*>(ar + (size_t)i * 4);
  const float es0 = __expf(lrelu(al4.x + ari.x));
  const float es1 = __expf(lrelu(al4.y + ari.y));
  const float es2 = __expf(lrelu(al4.z + ari.z));
  const float es3 = __expf(lrelu(al4.w + ari.w));

  const int g  = lane / LPG;
  const int cl = lane - g * LPG;
  const bool act = g < NG;
  const int hd = (cl * 8) / C;
  const float al_h = hd < 2 ? (hd == 0 ? al4.x : al4.y) : (hd == 2 ? al4.z : al4.w);
  const float es_h = hd < 2 ? (hd == 0 ? es0 : es1) : (hd == 2 ? es2 : es3);

  float t = 0.f;
  float acc[8];
#pragma unroll
  for (int k = 0; k < 8; ++k) acc[k] = 0.f;

  if (g == 0) {   // self-loop contribution (unnormalized)
    const uint4 hv = *reinterpret_cast<const uint4*>(h + (size_t)i * ROW + cl * 8);
    acc[0] = es_h * b2f_lo(hv.x); acc[1] = es_h * b2f_hi(hv.x);
    acc[2] = es_h * b2f_lo(hv.y); acc[3] = es_h * b2f_hi(hv.y);
    acc[4] = es_h * b2f_lo(hv.z); acc[5] = es_h * b2f_hi(hv.z);
    acc[6] = es_h * b2f_lo(hv.w); acc[7] = es_h * b2f_hi(hv.w);
  }

#define FMA8(W, HV) \
  acc[0] = fmaf(W, b2f_lo(HV.x), acc[0]); acc[1] = fmaf(W, b2f_hi(HV.x), acc[1]); \
  acc[2] = fmaf(W, b2f_lo(HV.y), acc[2]); acc[3] = fmaf(W, b2f_hi(HV.y), acc[3]); \
  acc[4] = fmaf(W, b2f_lo(HV.z), acc[4]); acc[5] = fmaf(W, b2f_hi(HV.z), acc[5]); \
  acc[6] = fmaf(W, b2f_lo(HV.w), acc[6]); acc[7] = fmaf(W, b2f_hi(HV.w), acc[7])
#define EDGE1(J) { \
  const float a_ = ar[(size_t)(J) * 4 + hd]; \
  const uint4 hv_ = *reinterpret_cast<const uint4*>(h + (size_t)(J) * ROW + cl * 8); \
  const float w_ = __expf(lrelu(al_h + a_)); \
  t += w_; \
  FMA8(w_, hv_); }

  if (act) {
    int e = s0 + g;
    int j0 = scol[e];                // padded scol: safe to LOAD past s1
    int j1 = scol[e + NG];
    int j2 = scol[e + 2 * NG];
    int j3 = scol[e + 3 * NG];
    for (; e + 3 * NG < s1; e += 4 * NG) {
      const int p0 = scol[e + 4 * NG];
      const int p1 = scol[e + 5 * NG];
      const int p2 = scol[e + 6 * NG];
      const int p3 = scol[e + 7 * NG];
      const float a0 = ar[(size_t)j0 * 4 + hd];
      const float a1 = ar[(size_t)j1 * 4 + hd];
      const float a2 = ar[(size_t)j2 * 4 + hd];
      const float a3 = ar[(size_t)j3 * 4 + hd];
      const uint4 h0_ = *reinterpret_cast<const uint4*>(h + (size_t)j0 * ROW + cl * 8);
      const uint4 h1_ = *reinterpret_cast<const uint4*>(h + (size_t)j1 * ROW + cl * 8);
      const uint4 h2_ = *reinterpret_cast<const uint4*>(h + (size_t)j2 * ROW + cl * 8);
      const uint4 h3_ = *reinterpret_cast<const uint4*>(h + (size_t)j3 * ROW + cl * 8);
      const float w0 = __expf(lrelu(al_h + a0));
      const float w1 = __expf(lrelu(al_h + a1));
      const float w2 = __expf(lrelu(al_h + a2));
      const float w3 = __expf(lrelu(al_h + a3));
      t += (w0 + w1) + (w2 + w3);
      FMA8(w0, h0_); FMA8(w1, h1_); FMA8(w2, h2_); FMA8(w3, h3_);
      j0 = p0; j1 = p1; j2 = p2; j3 = p3;
    }
    // remainder: up to 3 edges, prefetched indices j0..j2 are valid per guard
    if (e < s1) {
      EDGE1(j0)
      e += NG;
      if (e < s1) {
        EDGE1(j1)
        e += NG;
        if (e < s1) EDGE1(j2)
      }
    }
  }
#undef EDGE1
#undef FMA8

  if (CONCAT_RELU) {
    t += __shfl_xor(t, 32);            // combine the two groups ONLY
    const float inv = 1.f / (t + es_h + EPSV);
#pragma unroll
    for (int k = 0; k < 8; ++k) acc[k] *= inv;
#pragma unroll
    for (int k = 0; k < 8; ++k) acc[k] += __shfl_xor(acc[k], 32);
    if (g == 0) {
      const float4 blo = *reinterpret_cast<const float4*>(bias + cl * 8);
      const float4 bhi = *reinterpret_cast<const float4*>(bias + cl * 8 + 4);
      uint4 st;
      st.x = (unsigned)f2b(fmaxf(acc[0] + blo.x, 0.f)) |
             ((unsigned)f2b(fmaxf(acc[1] + blo.y, 0.f)) << 16);
      st.y = (unsigned)f2b(fmaxf(acc[2] + blo.z, 0.f)) |
             ((unsigned)f2b(fmaxf(acc[3] + blo.w, 0.f)) << 16);
      st.z = (unsigned)f2b(fmaxf(acc[4] + bhi.x, 0.f)) |
             ((unsigned)f2b(fmaxf(acc[5] + bhi.y, 0.f)) << 16);
      st.w = (unsigned)f2b(fmaxf(acc[6] + bhi.z, 0.f)) |
             ((unsigned)f2b(fmaxf(acc[7] + bhi.w, 0.f)) << 16);
      *reinterpret_cast<uint4*>((ushort_t*)outv + (size_t)i * ROW + cl * 8) = st;
    }
  } else {
    if (act) {
#pragma unroll
      for (int k = 0; k < 8; ++k) smA[wid][g][cl * 8 + k] = acc[k];
      smT[wid][g * LPG + cl] = t;
    }
    __syncthreads();
    if (lane < C) {
      const float es[4] = {es0, es1, es2, es3};
      float s = 0.f;
#pragma unroll
      for (int hh = 0; hh < HEADS; ++hh) {
        float den = es[hh];
#pragma unroll
        for (int gg = 0; gg < NG; ++gg)
          den += smT[wid][gg * LPG + hh * 5];   // ONE representative per group
        float chan = 0.f;
#pragma unroll
        for (int gg = 0; gg < NG; ++gg) chan += smA[wid][gg][hh * C + lane];
        s += chan / (den + EPSV);
      }
      ((float*)outv)[(size_t)i * C + lane] = s * 0.25f + bias[lane];
    }
  }
}

// ---- launch -------------------------------------------------------------------
extern "C" void kernel_launch(void* const* d_in, const int* in_sizes, int n_in,
                              void* d_out, int out_size, void* d_ws, size_t ws_size,
                              hipStream_t stream) {
  const float* x    = (const float*)d_in[0];
  const int*   ei   = (const int*)d_in[1];
  const float* w0   = (const float*)d_in[2];
  const float* att0 = (const float*)d_in[3];
  const float* b0   = (const float*)d_in[4];
  const float* w1   = (const float*)d_in[5];
  const float* att1 = (const float*)d_in[6];
  const float* b1   = (const float*)d_in[7];
  float* out = (float*)d_out;

  char* ws = (char*)d_ws;
  size_t off = 0;
  auto alloc = [&](size_t bytes) -> void* {
    void* p = ws + off;
    off += (bytes + 255) & ~(size_t)255;
    return p;
  };
  ushort_t* h0b = (ushort_t*)alloc((size_t)N_NODES * HC0 * 2);  // 15.4 MB
  ushort_t* o0b = (ushort_t*)alloc((size_t)N_NODES * HC0 * 2);  // 15.4 MB
  float* al0 = (float*)alloc((size_t)N_NODES * HEADS * 4);
  float* ar0 = (float*)alloc((size_t)N_NODES * HEADS * 4);
  ushort_t* w0t = (ushort_t*)alloc((size_t)HC0 * NFEAT * 2);    // 128 KB
  ushort_t* w1t = (ushort_t*)alloc((size_t)HC1 * HC0 * 2);      // 80 KB
  int* deg      = (int*)alloc((size_t)N_NODES * 4);
  int* fill     = (int*)alloc((size_t)N_NODES * 4);   // adjacent to deg
  int* rowstart = (int*)alloc((size_t)(N_NODES + 1) * 4);
  int* scol     = (int*)alloc((size_t)(N_EDGESN + 64) * 4);  // +64 pad: no clamps
  ushort_t* h1b = h0b;   // layer-0 h dead after layer-0 agg
  float* al1 = al0;
  float* ar1 = ar0;

  const int* srcp = ei;
  const int* dstp = ei + N_EDGESN;

  const int ztot = (int)(fill - deg) + N_NODES;     // covers deg + fill
  constexpr int PREPN = NFEAT * HC0 + HC0 * HC1;    // 106496 >= ztot
  prep_kernel<<<(PREPN + 255) / 256, 256, 0, stream>>>(w0, w1, w0t, w1t, deg, ztot);
  hist_kernel<<<(N_EDGESN + 255) / 256, 256, 0, stream>>>(srcp, deg, N_EDGESN);
  scan_kernel<<<1, 1024, 0, stream>>>(deg, rowstart, N_NODES);
  scatter_kernel<<<(N_EDGESN + 255) / 256, 256, 0, stream>>>(srcp, dstp, rowstart,
                                                             fill, scol, N_EDGESN);

  // layer 0: 625 blocks x 3 strips, B in regs (128 VGPR), att fused
  gemm_mfma3<4, 4, true, 1, 256><<<625, 256, 0, stream>>>(
      x, w0t, h0b, 625, att0, al0, ar0);
  gat_agg6<C0V, true><<<(N_NODES + 3) / 4, 256, 0, stream>>>(
      h0b, al0, ar0, rowstart, scol, b0, o0b, N_NODES);
  // layer 1: 938 blocks (128 thr) x <=2 strips, B in regs, att fused
  gemm_mfma3<5, 2, false, 2, 128><<<938, 128, 0, stream>>>(
      o0b, w1t, h1b, 938, att1, al1, ar1);
  gat_agg6<C1V, false><<<(N_NODES + 3) / 4, 256, 0, stream>>>(
      h1b, al1, ar1, rowstart, scol, b1, out, N_NODES);
}

// Round 15
// 171.984 us; speedup vs baseline: 1.2189x; 1.1363x over previous
//
#include <hip/hip_runtime.h>
#include <math.h>

#define N_NODES 30000
#define N_EDGESN 480000
#define NFEAT 256
#define HEADS 4
#define C0V 64
#define C1V 40
#define HC0 (HEADS*C0V)   // 256
#define HC1 (HEADS*C1V)   // 160
#define NEG_SLOPE 0.2f
#define EPSV 1e-16f
#define KDIM 256
#define KPAD 264

typedef unsigned short ushort_t;
typedef __attribute__((ext_vector_type(8))) short short8v;
typedef __attribute__((ext_vector_type(4))) float f32x4;

__device__ __forceinline__ float lrelu(float x) { return x >= 0.f ? x : x * NEG_SLOPE; }

__device__ __forceinline__ float b2f_lo(unsigned int u) {
  union { unsigned int u; float f; } v; v.u = u << 16; return v.f;
}
__device__ __forceinline__ float b2f_hi(unsigned int u) {
  union { unsigned int u; float f; } v; v.u = u & 0xffff0000u; return v.f;
}
__device__ __forceinline__ unsigned short f2b(float f) {
  union { float f; unsigned int u; } v; v.f = f;
  unsigned int u = v.u + 0x7FFFu + ((v.u >> 16) & 1u);   // round-nearest-even
  return (unsigned short)(u >> 16);
}

// ---- prep: weight transposes + zero deg/fill/counter, one dispatch ------------
__global__ __launch_bounds__(256) void prep_kernel(const float* __restrict__ W0,
    const float* __restrict__ W1, ushort_t* __restrict__ W0t,
    ushort_t* __restrict__ W1t, int* __restrict__ zp, int zn) {
  const int idx = blockIdx.x * 256 + threadIdx.x;
  constexpr int T0 = NFEAT * HC0;   // 65536
  constexpr int T1 = HC0 * HC1;     // 40960
  if (idx < T0) {
    const int k = idx / HC0, nf = idx - k * HC0;
    W0t[(size_t)nf * NFEAT + k] = f2b(W0[idx]);
  } else if (idx < T0 + T1) {
    const int i2 = idx - T0;
    const int k = i2 / HC1, nf = i2 - k * HC1;
    W1t[(size_t)nf * HC0 + k] = f2b(W1[i2]);
  }
  if (idx < zn) zp[idx] = 0;
}

// ---- MFMA GEMM v3: B in registers, multi-strip blocks, double-buffered A ------
template <int NFW, int CG, bool A_F32, int FUSE, int NT>
__global__ __launch_bounds__(NT) void gemm_mfma3(const void* __restrict__ Ap,
    const ushort_t* __restrict__ Wt, ushort_t* __restrict__ C, int nblk,
    const float* __restrict__ att, float* __restrict__ al, float* __restrict__ ar) {
  constexpr int S = N_NODES / 16;           // 1875 strips (M % 16 == 0)
  constexpr int N = CG * NFW * 16;
  constexpr int NCH = 16 * (KDIM / 8) / NT; // staging chunks per thread
  __shared__ ushort_t As[2][16][KPAD];
  const int tid = threadIdx.x;
  const int lane = tid & 63, cg = tid >> 6;
  const int r_a = lane & 15, kg = lane >> 4;

  short8v B[8][NFW];
#pragma unroll
  for (int ks = 0; ks < 8; ++ks)
#pragma unroll
    for (int f = 0; f < NFW; ++f)
      B[ks][f] = *reinterpret_cast<const short8v*>(
          Wt + (size_t)((cg * NFW + f) * 16 + r_a) * KDIM + ks * 32 + kg * 8);

#define STAGE_LOAD(STRIP, STG)                                                   \
  _Pragma("unroll")                                                              \
  for (int q = 0; q < NCH; ++q) {                                                \
    const int c = tid + q * NT;                                                  \
    const int r = c >> 5, ko = (c & 31) * 8;                                     \
    if (A_F32) {                                                                 \
      const float* A = (const float*)Ap + (size_t)((STRIP) * 16 + r) * KDIM + ko;\
      const float4 lo = *reinterpret_cast<const float4*>(A);                     \
      const float4 hi = *reinterpret_cast<const float4*>(A + 4);                 \
      STG[q].x = (unsigned)f2b(lo.x) | ((unsigned)f2b(lo.y) << 16);              \
      STG[q].y = (unsigned)f2b(lo.z) | ((unsigned)f2b(lo.w) << 16);              \
      STG[q].z = (unsigned)f2b(hi.x) | ((unsigned)f2b(hi.y) << 16);              \
      STG[q].w = (unsigned)f2b(hi.z) | ((unsigned)f2b(hi.w) << 16);              \
    } else {                                                                     \
      STG[q] = *reinterpret_cast<const uint4*>(                                  \
          (const ushort_t*)Ap + (size_t)((STRIP) * 16 + r) * KDIM + ko);         \
    }                                                                            \
  }
#define STAGE_WRITE(BUF, STG)                                                    \
  _Pragma("unroll")                                                              \
  for (int q = 0; q < NCH; ++q) {                                                \
    const int c = tid + q * NT;                                                  \
    const int r = c >> 5, ko = (c & 31) * 8;                                     \
    *reinterpret_cast<uint4*>(&As[BUF][r][ko]) = STG[q];                         \
  }

  int strip = blockIdx.x;
  {
    uint4 stg[NCH];
    STAGE_LOAD(strip, stg)
    STAGE_WRITE(0, stg)
  }
  __syncthreads();

  int buf = 0;
  while (true) {
    const int next = strip + nblk;
    const bool has_next = next < S;
    uint4 stg[NCH];
    if (has_next) { STAGE_LOAD(next, stg) }   // loads in flight during compute

    f32x4 acc[NFW];
#pragma unroll
    for (int f = 0; f < NFW; ++f) acc[f] = (f32x4){0.f, 0.f, 0.f, 0.f};
#pragma unroll
    for (int ks = 0; ks < 8; ++ks) {
      const short8v a =
          *reinterpret_cast<const short8v*>(&As[buf][r_a][ks * 32 + kg * 8]);
#pragma unroll
      for (int f = 0; f < NFW; ++f)
        acc[f] = __builtin_amdgcn_mfma_f32_16x16x32_bf16(a, B[ks][f], acc[f], 0, 0, 0);
    }
    const int row0 = strip * 16;
#pragma unroll
    for (int f = 0; f < NFW; ++f) {
#pragma unroll
      for (int r = 0; r < 4; ++r) {
        C[(size_t)(row0 + kg * 4 + r) * N + (cg * NFW + f) * 16 + r_a] =
            f2b(acc[f][r]);
      }
    }
    if (FUSE == 1) {
      float hpl[4] = {0.f, 0.f, 0.f, 0.f}, hpr[4] = {0.f, 0.f, 0.f, 0.f};
#pragma unroll
      for (int f = 0; f < NFW; ++f) {
        const int cc = f * 16 + r_a;
        const float wlv = att[cg * 128 + cc];
        const float wrv = att[cg * 128 + 64 + cc];
#pragma unroll
        for (int r = 0; r < 4; ++r) {
          hpl[r] = fmaf(acc[f][r], wlv, hpl[r]);
          hpr[r] = fmaf(acc[f][r], wrv, hpr[r]);
        }
      }
#pragma unroll
      for (int o = 1; o < 16; o <<= 1) {
#pragma unroll
        for (int r = 0; r < 4; ++r) {
          hpl[r] += __shfl_xor(hpl[r], o);
          hpr[r] += __shfl_xor(hpr[r], o);
        }
      }
      if (r_a == 0) {
#pragma unroll
        for (int r = 0; r < 4; ++r) {
          const int row = row0 + kg * 4 + r;
          al[(size_t)row * 4 + cg] = hpl[r];
          ar[(size_t)row * 4 + cg] = hpr[r];
        }
      }
    } else if (FUSE == 2) {
      float hpa[4] = {0,0,0,0}, hpb[4] = {0,0,0,0};
      float hra[4] = {0,0,0,0}, hrb[4] = {0,0,0,0};
#pragma unroll
      for (int f = 0; f < NFW; ++f) {
        const int col = cg * 80 + f * 16 + r_a;
        const int hd = col / 40;
        const int cc = col - hd * 40;
        const float wlv = att[hd * 80 + cc];
        const float wrv = att[hd * 80 + 40 + cc];
        const bool isB = (hd & 1);
#pragma unroll
        for (int r = 0; r < 4; ++r) {
          const float v = acc[f][r];
          if (isB) { hpb[r] = fmaf(v, wlv, hpb[r]); hrb[r] = fmaf(v, wrv, hrb[r]); }
          else     { hpa[r] = fmaf(v, wlv, hpa[r]); hra[r] = fmaf(v, wrv, hra[r]); }
        }
      }
#pragma unroll
      for (int o = 1; o < 16; o <<= 1) {
#pragma unroll
        for (int r = 0; r < 4; ++r) {
          hpa[r] += __shfl_xor(hpa[r], o); hpb[r] += __shfl_xor(hpb[r], o);
          hra[r] += __shfl_xor(hra[r], o); hrb[r] += __shfl_xor(hrb[r], o);
        }
      }
      if (r_a == 0) {
#pragma unroll
        for (int r = 0; r < 4; ++r) {
          const int row = row0 + kg * 4 + r;
          al[(size_t)row * 4 + cg * 2 + 0] = hpa[r];
          al[(size_t)row * 4 + cg * 2 + 1] = hpb[r];
          ar[(size_t)row * 4 + cg * 2 + 0] = hra[r];
          ar[(size_t)row * 4 + cg * 2 + 1] = hrb[r];
        }
      }
    }

    if (!has_next) break;
    STAGE_WRITE(buf ^ 1, stg)
    __syncthreads();
    strip = next; buf ^= 1;
  }
#undef STAGE_LOAD
#undef STAGE_WRITE
}

// ---- CSR build ----------------------------------------------------------------
__global__ void hist_kernel(const int* __restrict__ src, int* __restrict__ deg, int E) {
  const int e = blockIdx.x * blockDim.x + threadIdx.x;
  if (e < E) atomicAdd(&deg[src[e]], 1);
}

// Parallel segment allocator (replaces serial single-block scan): segments in
// ARBITRARY order, contiguous & disjoint — sufficient for CSR. Per wave: shfl
// inclusive scan of 64 degrees, lane 63 atomicAdd's the wave total (469 atomics
// total), all lanes write base + exclusive prefix.
__global__ __launch_bounds__(256) void alloc_kernel(const int* __restrict__ deg,
    int* __restrict__ rowstart, int* __restrict__ counter, int n) {
  const int i = blockIdx.x * 256 + threadIdx.x;
  const int lane = threadIdx.x & 63;
  const int d = (i < n) ? deg[i] : 0;
  int x = d;
#pragma unroll
  for (int o = 1; o < 64; o <<= 1) { int y = __shfl_up(x, o); if (lane >= o) x += y; }
  int base = 0;
  if (lane == 63) base = atomicAdd(counter, x);
  base = __shfl(base, 63);
  if (i < n) rowstart[i] = base + x - d;
}

__global__ void scatter_kernel(const int* __restrict__ src, const int* __restrict__ dst,
    const int* __restrict__ rowstart, int* __restrict__ fill, int* __restrict__ scol,
    int E) {
  const int e = blockIdx.x * blockDim.x + threadIdx.x;
  if (e < E) {
    const int r = src[e];
    const int pos = rowstart[r] + atomicAdd(&fill[r], 1);
    scol[pos] = dst[e];
  }
}

// ---- agg v6e: single pass, normalize late, unroll-4, s1 = s0 + deg[i] ---------
template <int C, bool CONCAT_RELU>
__global__ __launch_bounds__(256) void gat_agg6(const ushort_t* __restrict__ h,
    const float* __restrict__ al, const float* __restrict__ ar,
    const int* __restrict__ rowstart, const int* __restrict__ deg,
    const int* __restrict__ scol, const float* __restrict__ bias,
    void* __restrict__ outv, int n) {
  constexpr int ROW = HEADS * C;     // 256 / 160
  constexpr int LPG = ROW / 8;       // lanes per group: 32 / 20
  constexpr int NG  = 64 / LPG;      // groups: 2 / 3
  __shared__ float smA[CONCAT_RELU ? 1 : 4][CONCAT_RELU ? 1 : NG]
                      [CONCAT_RELU ? 1 : ROW];
  __shared__ float smT[CONCAT_RELU ? 1 : 4][CONCAT_RELU ? 1 : NG * LPG];
  const int wid = threadIdx.x >> 6, lane = threadIdx.x & 63;
  const int i = blockIdx.x * 4 + wid;
  if (i >= n) return;                // never taken (30000 % 4 == 0)
  const int s0 = rowstart[i];
  const int s1 = s0 + deg[i];

  const float4 al4 = *reinterpret_cast<const float4*>(al + (size_t)i * 4);
  const float4 ari = *reinterpret_cast<const float4*>(ar + (size_t)i * 4);
  const float es0 = __expf(lrelu(al4.x + ari.x));
  const float es1 = __expf(lrelu(al4.y + ari.y));
  const float es2 = __expf(lrelu(al4.z + ari.z));
  const float es3 = __expf(lrelu(al4.w + ari.w));

  const int g  = lane / LPG;
  const int cl = lane - g * LPG;
  const bool act = g < NG;
  const int hd = (cl * 8) / C;
  const float al_h = hd < 2 ? (hd == 0 ? al4.x : al4.y) : (hd == 2 ? al4.z : al4.w);
  const float es_h = hd < 2 ? (hd == 0 ? es0 : es1) : (hd == 2 ? es2 : es3);

  float t = 0.f;
  float acc[8];
#pragma unroll
  for (int k = 0; k < 8; ++k) acc[k] = 0.f;

  if (g == 0) {   // self-loop contribution (unnormalized)
    const uint4 hv = *reinterpret_cast<const uint4*>(h + (size_t)i * ROW + cl * 8);
    acc[0] = es_h * b2f_lo(hv.x); acc[1] = es_h * b2f_hi(hv.x);
    acc[2] = es_h * b2f_lo(hv.y); acc[3] = es_h * b2f_hi(hv.y);
    acc[4] = es_h * b2f_lo(hv.z); acc[5] = es_h * b2f_hi(hv.z);
    acc[6] = es_h * b2f_lo(hv.w); acc[7] = es_h * b2f_hi(hv.w);
  }

#define FMA8(W, HV) \
  acc[0] = fmaf(W, b2f_lo(HV.x), acc[0]); acc[1] = fmaf(W, b2f_hi(HV.x), acc[1]); \
  acc[2] = fmaf(W, b2f_lo(HV.y), acc[2]); acc[3] = fmaf(W, b2f_hi(HV.y), acc[3]); \
  acc[4] = fmaf(W, b2f_lo(HV.z), acc[4]); acc[5] = fmaf(W, b2f_hi(HV.z), acc[5]); \
  acc[6] = fmaf(W, b2f_lo(HV.w), acc[6]); acc[7] = fmaf(W, b2f_hi(HV.w), acc[7])
#define EDGE1(J) { \
  const float a_ = ar[(size_t)(J) * 4 + hd]; \
  const uint4 hv_ = *reinterpret_cast<const uint4*>(h + (size_t)(J) * ROW + cl * 8); \
  const float w_ = __expf(lrelu(al_h + a_)); \
  t += w_; \
  FMA8(w_, hv_); }

  if (act) {
    int e = s0 + g;
    int j0 = scol[e];                // padded scol: safe to LOAD past s1
    int j1 = scol[e + NG];
    int j2 = scol[e + 2 * NG];
    int j3 = scol[e + 3 * NG];
    for (; e + 3 * NG < s1; e += 4 * NG) {
      const int p0 = scol[e + 4 * NG];
      const int p1 = scol[e + 5 * NG];
      const int p2 = scol[e + 6 * NG];
      const int p3 = scol[e + 7 * NG];
      const float a0 = ar[(size_t)j0 * 4 + hd];
      const float a1 = ar[(size_t)j1 * 4 + hd];
      const float a2 = ar[(size_t)j2 * 4 + hd];
      const float a3 = ar[(size_t)j3 * 4 + hd];
      const uint4 h0_ = *reinterpret_cast<const uint4*>(h + (size_t)j0 * ROW + cl * 8);
      const uint4 h1_ = *reinterpret_cast<const uint4*>(h + (size_t)j1 * ROW + cl * 8);
      const uint4 h2_ = *reinterpret_cast<const uint4*>(h + (size_t)j2 * ROW + cl * 8);
      const uint4 h3_ = *reinterpret_cast<const uint4*>(h + (size_t)j3 * ROW + cl * 8);
      const float w0 = __expf(lrelu(al_h + a0));
      const float w1 = __expf(lrelu(al_h + a1));
      const float w2 = __expf(lrelu(al_h + a2));
      const float w3 = __expf(lrelu(al_h + a3));
      t += (w0 + w1) + (w2 + w3);
      FMA8(w0, h0_); FMA8(w1, h1_); FMA8(w2, h2_); FMA8(w3, h3_);
      j0 = p0; j1 = p1; j2 = p2; j3 = p3;
    }
    if (e < s1) {
      EDGE1(j0)
      e += NG;
      if (e < s1) {
        EDGE1(j1)
        e += NG;
        if (e < s1) EDGE1(j2)
      }
    }
  }
#undef EDGE1
#undef FMA8

  if (CONCAT_RELU) {
    t += __shfl_xor(t, 32);            // combine the two groups ONLY
    const float inv = 1.f / (t + es_h + EPSV);
#pragma unroll
    for (int k = 0; k < 8; ++k) acc[k] *= inv;
#pragma unroll
    for (int k = 0; k < 8; ++k) acc[k] += __shfl_xor(acc[k], 32);
    if (g == 0) {
      const float4 blo = *reinterpret_cast<const float4*>(bias + cl * 8);
      const float4 bhi = *reinterpret_cast<const float4*>(bias + cl * 8 + 4);
      uint4 st;
      st.x = (unsigned)f2b(fmaxf(acc[0] + blo.x, 0.f)) |
             ((unsigned)f2b(fmaxf(acc[1] + blo.y, 0.f)) << 16);
      st.y = (unsigned)f2b(fmaxf(acc[2] + blo.z, 0.f)) |
             ((unsigned)f2b(fmaxf(acc[3] + blo.w, 0.f)) << 16);
      st.z = (unsigned)f2b(fmaxf(acc[4] + bhi.x, 0.f)) |
             ((unsigned)f2b(fmaxf(acc[5] + bhi.y, 0.f)) << 16);
      st.w = (unsigned)f2b(fmaxf(acc[6] + bhi.z, 0.f)) |
             ((unsigned)f2b(fmaxf(acc[7] + bhi.w, 0.f)) << 16);
      *reinterpret_cast<uint4*>((ushort_t*)outv + (size_t)i * ROW + cl * 8) = st;
    }
  } else {
    if (act) {
#pragma unroll
      for (int k = 0; k < 8; ++k) smA[wid][g][cl * 8 + k] = acc[k];
      smT[wid][g * LPG + cl] = t;
    }
    __syncthreads();
    if (lane < C) {
      const float es[4] = {es0, es1, es2, es3};
      float s = 0.f;
#pragma unroll
      for (int hh = 0; hh < HEADS; ++hh) {
        float den = es[hh];
#pragma unroll
        for (int gg = 0; gg < NG; ++gg)
          den += smT[wid][gg * LPG + hh * 5];   // ONE representative per group
        float chan = 0.f;
#pragma unroll
        for (int gg = 0; gg < NG; ++gg) chan += smA[wid][gg][hh * C + lane];
        s += chan / (den + EPSV);
      }
      ((float*)outv)[(size_t)i * C + lane] = s * 0.25f + bias[lane];
    }
  }
}

// ---- launch -------------------------------------------------------------------
extern "C" void kernel_launch(void* const* d_in, const int* in_sizes, int n_in,
                              void* d_out, int out_size, void* d_ws, size_t ws_size,
                              hipStream_t stream) {
  const float* x    = (const float*)d_in[0];
  const int*   ei   = (const int*)d_in[1];
  const float* w0   = (const float*)d_in[2];
  const float* att0 = (const float*)d_in[3];
  const float* b0   = (const float*)d_in[4];
  const float* w1   = (const float*)d_in[5];
  const float* att1 = (const float*)d_in[6];
  const float* b1   = (const float*)d_in[7];
  float* out = (float*)d_out;

  char* ws = (char*)d_ws;
  size_t off = 0;
  auto alloc = [&](size_t bytes) -> void* {
    void* p = ws + off;
    off += (bytes + 255) & ~(size_t)255;
    return p;
  };
  ushort_t* h0b = (ushort_t*)alloc((size_t)N_NODES * HC0 * 2);  // 15.4 MB
  ushort_t* o0b = (ushort_t*)alloc((size_t)N_NODES * HC0 * 2);  // 15.4 MB
  float* al0 = (float*)alloc((size_t)N_NODES * HEADS * 4);
  float* ar0 = (float*)alloc((size_t)N_NODES * HEADS * 4);
  ushort_t* w0t = (ushort_t*)alloc((size_t)HC0 * NFEAT * 2);    // 128 KB
  ushort_t* w1t = (ushort_t*)alloc((size_t)HC1 * HC0 * 2);      // 80 KB
  int* deg      = (int*)alloc((size_t)N_NODES * 4);
  int* fill     = (int*)alloc((size_t)N_NODES * 4);
  int* counter  = (int*)alloc(256);                   // adjacent: one zero range
  int* rowstart = (int*)alloc((size_t)N_NODES * 4);
  int* scol     = (int*)alloc((size_t)(N_EDGESN + 64) * 4);  // +64 pad: no clamps
  ushort_t* h1b = h0b;   // layer-0 h dead after layer-0 agg
  float* al1 = al0;
  float* ar1 = ar0;

  const int* srcp = ei;
  const int* dstp = ei + N_EDGESN;

  const int ztot = (int)(counter - deg) + 1;          // deg + fill + counter
  constexpr int PREPN = NFEAT * HC0 + HC0 * HC1;      // 106496 >= ztot
  prep_kernel<<<(PREPN + 255) / 256, 256, 0, stream>>>(w0, w1, w0t, w1t, deg, ztot);
  hist_kernel<<<(N_EDGESN + 255) / 256, 256, 0, stream>>>(srcp, deg, N_EDGESN);
  alloc_kernel<<<(N_NODES + 255) / 256, 256, 0, stream>>>(deg, rowstart, counter,
                                                          N_NODES);
  scatter_kernel<<<(N_EDGESN + 255) / 256, 256, 0, stream>>>(srcp, dstp, rowstart,
                                                             fill, scol, N_EDGESN);

  // layer 0: 625 blocks x 3 strips, B in regs (128 VGPR), att fused
  gemm_mfma3<4, 4, true, 1, 256><<<625, 256, 0, stream>>>(
      x, w0t, h0b, 625, att0, al0, ar0);
  gat_agg6<C0V, true><<<(N_NODES + 3) / 4, 256, 0, stream>>>(
      h0b, al0, ar0, rowstart, deg, scol, b0, o0b, N_NODES);
  // layer 1: 938 blocks (128 thr) x <=2 strips, B in regs, att fused
  gemm_mfma3<5, 2, false, 2, 128><<<938, 128, 0, stream>>>(
      o0b, w1t, h1b, 938, att1, al1, ar1);
  gat_agg6<C1V, false><<<(N_NODES + 3) / 4, 256, 0, stream>>>(
      h1b, al1, ar1, rowstart, deg, scol, b1, out, N_NODES);
}